// Round 5
// baseline (1388.444 us; speedup 1.0000x reference)
//
#include <hip/hip_runtime.h>
#include <hip/hip_bf16.h>
#include <cstdint>
#include <cstddef>

// N=20000, E=100000, G=32, HID=64, HEADS=8, HC=64, HO=512, L=3, K=4. All fp32.
// e = ea@We+be only appears inside q·(k+e) and Σ a(v+e):
//   q·e|_h = ea · qe[dst]|_h,  qe[d][h*64+j] = Σ_c q[d][64h+c] We[j][64h+c]
//   Σ a e  = (Σ a ea) @ We + (Σ a) be   -> all We GEMMs at N-level.
// R4: edge_init split (transcendentals 1 thread/edge). R5: k_node_finish was
// 115us (We streamed from global in inner loop, 29% occ) -> tiled LDS GEMM;
// v head-sum folded into k_attn_agg via shfl (vsum N*64 replaces vagg N*512).

// ---------------- embed / init ----------------

__global__ void __launch_bounds__(256) k_node_embed(
    const float* __restrict__ x, const float* __restrict__ neW, const float* __restrict__ neb,
    float* __restrict__ h, int N)
{
    int idx = blockIdx.x * 256 + threadIdx.x;
    int n = idx >> 6, c = idx & 63;
    if (n >= N) return;
    float acc = neb[c];
    #pragma unroll
    for (int j = 0; j < 7; ++j) acc += x[(size_t)n * 7 + j] * neW[j * 64 + c];
    h[(size_t)n * 64 + c] = fmaxf(acc, 0.f);
}

__global__ void __launch_bounds__(256) k_edge_w(
    const float* __restrict__ x,
    const float* __restrict__ means, const float* __restrict__ log_stds,
    const int* __restrict__ src, const int* __restrict__ dst,
    float* __restrict__ wbuf, int E)
{
    int e = blockIdx.x * 256 + threadIdx.x;
    if (e >= E) return;
    int s = src[e], d = dst[e];
    const float* ps = x + (size_t)s * 7;
    const float* pd = x + (size_t)d * 7;
    float slx = ps[0], sly = ps[1], srx = ps[2], sry = ps[3];
    float dlx = pd[0], dly = pd[1], drx = pd[2], dry = pd[3];
    float u[8];
    float rx, ry;
    rx = dlx - slx; ry = dly - sly; u[0] = sqrtf(rx*rx + ry*ry); u[1] = atan2f(ry, rx);
    rx = dlx - srx; ry = dly - sry; u[2] = sqrtf(rx*rx + ry*ry); u[3] = atan2f(ry, rx);
    rx = drx - slx; ry = dry - sly; u[4] = sqrtf(rx*rx + ry*ry); u[5] = atan2f(ry, rx);
    rx = drx - srx; ry = dry - sry; u[6] = sqrtf(rx*rx + ry*ry); u[7] = atan2f(ry, rx);
    #pragma unroll
    for (int kk = 0; kk < 4; ++kk) {
        float ssum = 0.f;
        #pragma unroll
        for (int dd = 0; dd < 8; ++dd) {
            float stdv = expf(log_stds[kk*8+dd]) + 1e-6f;
            float z = (u[dd] - means[kk*8+dd]) / stdv;
            ssum += z * z;
        }
        wbuf[(size_t)e*4 + kk] = expf(-0.5f * ssum);
    }
}

__global__ void __launch_bounds__(256) k_edge_ea(
    const float* __restrict__ edge_attr, const float* __restrict__ wbuf,
    const float* __restrict__ spW, const float* __restrict__ spb,
    const float* __restrict__ eeW, const float* __restrict__ eeb,
    float* __restrict__ ea, int E)
{
    int idx = blockIdx.x * 256 + threadIdx.x;
    int e = idx >> 6, c = idx & 63;
    if (e >= E) return;
    float acce = eeb[c];
    #pragma unroll
    for (int j = 0; j < 4; ++j) acce += edge_attr[(size_t)e*4 + j] * eeW[j*64 + c];
    float accs = spb[c];
    #pragma unroll
    for (int j = 0; j < 4; ++j) accs += wbuf[(size_t)e*4 + j] * spW[j*64 + c];
    ea[(size_t)e*64 + c] = fmaxf(acce, 0.f) + fmaxf(accs, 0.f);
}

// ---------------- CSR build ----------------

__global__ void __launch_bounds__(256) k_hist(
    const int* __restrict__ dst, int* __restrict__ deg, int E)
{
    int e = blockIdx.x * 256 + threadIdx.x;
    if (e < E) atomicAdd(deg + dst[e], 1);
}

__global__ void __launch_bounds__(1024) k_scan(
    const int* __restrict__ deg, int* __restrict__ ptr, int* __restrict__ headw, int N)
{
    __shared__ int part[1024];
    int t = threadIdx.x;
    int per = (N + 1023) / 1024;
    int s = 0;
    for (int i = 0; i < per; ++i) { int idx = t*per + i; if (idx < N) s += deg[idx]; }
    part[t] = s;
    __syncthreads();
    for (int off = 1; off < 1024; off <<= 1) {
        int v = (t >= off) ? part[t - off] : 0;
        __syncthreads();
        part[t] += v;
        __syncthreads();
    }
    int base = (t > 0) ? part[t - 1] : 0;
    for (int i = 0; i < per; ++i) {
        int idx = t*per + i;
        if (idx < N) { ptr[idx] = base; headw[idx] = base; base += deg[idx]; }
    }
    if (t == 1023) ptr[N] = part[1023];
}

__global__ void __launch_bounds__(256) k_scatter(
    const int* __restrict__ dst, int* __restrict__ headw, int* __restrict__ perm, int E)
{
    int e = blockIdx.x * 256 + threadIdx.x;
    if (e < E) {
        int pos = atomicAdd(headw + dst[e], 1);
        perm[pos] = e;
    }
}

// ---------------- GEMMs ----------------

__global__ void __launch_bounds__(256) k_gemm512_r32(
    const float* __restrict__ X, const float* __restrict__ W, const float* __restrict__ bias,
    float* __restrict__ Y, int M)
{
    __shared__ __align__(16) float xs[32][64];
    int tid = threadIdx.x;
    int r0 = blockIdx.x * 32;
    for (int i = tid; i < 2048; i += 256) {
        int r = i >> 6, c = i & 63;
        int rr = r0 + r;
        xs[r][c] = (rr < M) ? X[(size_t)rr * 64 + c] : 0.f;
    }
    __syncthreads();
    int wv = tid >> 6, lane = tid & 63;
    int c0 = lane * 8;
    float acc[8][8];
    float4 b0 = *(const float4*)(bias + c0);
    float4 b1 = *(const float4*)(bias + c0 + 4);
    #pragma unroll
    for (int t = 0; t < 8; ++t) {
        acc[t][0]=b0.x; acc[t][1]=b0.y; acc[t][2]=b0.z; acc[t][3]=b0.w;
        acc[t][4]=b1.x; acc[t][5]=b1.y; acc[t][6]=b1.z; acc[t][7]=b1.w;
    }
    #pragma unroll 2
    for (int j = 0; j < 64; ++j) {
        float4 wa = *(const float4*)(W + (size_t)j*512 + c0);
        float4 wb = *(const float4*)(W + (size_t)j*512 + c0 + 4);
        #pragma unroll
        for (int t = 0; t < 8; ++t) {
            float a = xs[wv*8 + t][j];
            acc[t][0] += a*wa.x; acc[t][1] += a*wa.y; acc[t][2] += a*wa.z; acc[t][3] += a*wa.w;
            acc[t][4] += a*wb.x; acc[t][5] += a*wb.y; acc[t][6] += a*wb.z; acc[t][7] += a*wb.w;
        }
    }
    #pragma unroll
    for (int t = 0; t < 8; ++t) {
        int r = r0 + wv*8 + t;
        if (r < M) {
            float4 o0 = {acc[t][0],acc[t][1],acc[t][2],acc[t][3]};
            float4 o1 = {acc[t][4],acc[t][5],acc[t][6],acc[t][7]};
            *(float4*)(Y + (size_t)r*512 + c0)     = o0;
            *(float4*)(Y + (size_t)r*512 + c0 + 4) = o1;
        }
    }
}

// qe[d][h*64+j] = sum_c q[d][64h+c] * We[j][64h+c].  grid: ((N+31)/32, 8)
__global__ void __launch_bounds__(256) k_qe(
    const float* __restrict__ q, const float* __restrict__ We,
    float* __restrict__ qe, int N)
{
    __shared__ __align__(16) float qlds[32][64];
    __shared__ float welds[64][65];
    int tid = threadIdx.x;
    int h = blockIdx.y;
    int n0 = blockIdx.x * 32;
    for (int i = tid; i < 2048; i += 256) {
        int r = i >> 6, c = i & 63;
        int n = n0 + r;
        qlds[r][c] = (n < N) ? q[(size_t)n*512 + h*64 + c] : 0.f;
    }
    for (int i = tid; i < 4096; i += 256) {
        int j = i >> 6, c = i & 63;
        welds[j][c] = We[(size_t)j*512 + h*64 + c];
    }
    __syncthreads();
    int wv = tid >> 6, lane = tid & 63;   // lane = j
    float acc[8];
    #pragma unroll
    for (int r = 0; r < 8; ++r) acc[r] = 0.f;
    #pragma unroll 4
    for (int c = 0; c < 64; ++c) {
        float w = welds[lane][c];
        #pragma unroll
        for (int r = 0; r < 8; ++r) acc[r] += qlds[wv*8 + r][c] * w;
    }
    #pragma unroll
    for (int r = 0; r < 8; ++r) {
        int n = n0 + wv*8 + r;
        if (n < N) qe[(size_t)n*512 + h*64 + lane] = acc[r];
    }
}

// ---------------- CSR-fused attention ----------------

__global__ void __launch_bounds__(256) k_attn_alpha(
    const float* __restrict__ q, const float* __restrict__ k, const float* __restrict__ qe,
    const float* __restrict__ be, const float* __restrict__ ea,
    const int* __restrict__ ptr, const int* __restrict__ perm, const int* __restrict__ srcp,
    float* __restrict__ alpha, float* __restrict__ mbuf, float* __restrict__ dbuf, int N)
{
    int wv = threadIdx.x >> 6, lane = threadIdx.x & 63;
    int n = blockIdx.x * 4 + wv;
    if (n >= N) return;
    int h = lane >> 3, p = lane & 7;
    int b = ptr[n], e_ = ptr[n + 1];
    const float4* qp = (const float4*)(q + (size_t)n*512 + lane*8);
    float4 q0 = qp[0], q1 = qp[1];
    const float4* qep = (const float4*)(qe + (size_t)n*512 + lane*8);
    float4 g0 = qep[0], g1 = qep[1];
    const float4* bep = (const float4*)(be + lane*8);
    float4 b0 = bep[0], b1 = bep[1];
    float qbe = q0.x*b0.x + q0.y*b0.y + q0.z*b0.z + q0.w*b0.w
              + q1.x*b1.x + q1.y*b1.y + q1.z*b1.z + q1.w*b1.w;
    qbe += __shfl_xor(qbe, 1);
    qbe += __shfl_xor(qbe, 2);
    qbe += __shfl_xor(qbe, 4);
    float m = -3.4e38f, den = 0.f;
    for (int it = b; it < e_; ++it) {
        int e = perm[it];
        int s = srcp[e];
        const float4* kp = (const float4*)(k + (size_t)s*512 + lane*8);
        float4 k0 = kp[0], k1 = kp[1];
        const float4* ap = (const float4*)(ea + (size_t)e*64 + p*8);
        float4 a0 = ap[0], a1 = ap[1];
        float t = q0.x*k0.x + q0.y*k0.y + q0.z*k0.z + q0.w*k0.w
                + q1.x*k1.x + q1.y*k1.y + q1.z*k1.z + q1.w*k1.w
                + a0.x*g0.x + a0.y*g0.y + a0.z*g0.z + a0.w*g0.w
                + a1.x*g1.x + a1.y*g1.y + a1.z*g1.z + a1.w*g1.w;
        t += __shfl_xor(t, 1);
        t += __shfl_xor(t, 2);
        t += __shfl_xor(t, 4);
        float al = 0.125f * (t + qbe);
        float mn = fmaxf(m, al);
        den = den * expf(m - mn) + expf(al - mn);
        m = mn;
        if (p == 0) alpha[(size_t)e*8 + h] = al;
    }
    if (p == 0) {
        mbuf[(size_t)n*8 + h] = m;
        dbuf[(size_t)n*8 + h] = den;
    }
}

// vsum[n][cc] = Σ_h Σ_e a v[s][64h+cc] (head-reduced in-register via shfl);
// tbuf[n][h*64+j] = Σ a_h ea[j]; sbuf[n][h] = Σ a_h.
__global__ void __launch_bounds__(256) k_attn_agg(
    const float* __restrict__ alpha, const float* __restrict__ mbuf, const float* __restrict__ dbuf,
    const float* __restrict__ v, const float* __restrict__ ea,
    const int* __restrict__ ptr, const int* __restrict__ perm, const int* __restrict__ srcp,
    float* __restrict__ vsum, float* __restrict__ tbuf, float* __restrict__ sbuf, int N)
{
    int wv = threadIdx.x >> 6, lane = threadIdx.x & 63;
    int n = blockIdx.x * 4 + wv;
    if (n >= N) return;
    int h = lane >> 3, p = lane & 7;
    int b = ptr[n], e_ = ptr[n + 1];
    float m = mbuf[(size_t)n*8 + h];
    float inv = 0.125f / (dbuf[(size_t)n*8 + h] + 1e-16f);   // 1/HEADS folded in
    float vacc[8], tacc[8];
    #pragma unroll
    for (int i = 0; i < 8; ++i) { vacc[i] = 0.f; tacc[i] = 0.f; }
    float sacc = 0.f;
    for (int it = b; it < e_; ++it) {
        int e = perm[it];
        int s = srcp[e];
        float a = expf(alpha[(size_t)e*8 + h] - m) * inv;
        sacc += a;
        const float4* vp = (const float4*)(v + (size_t)s*512 + lane*8);
        float4 v0 = vp[0], v1 = vp[1];
        const float4* ap = (const float4*)(ea + (size_t)e*64 + p*8);
        float4 a0 = ap[0], a1 = ap[1];
        vacc[0] += a*v0.x; vacc[1] += a*v0.y; vacc[2] += a*v0.z; vacc[3] += a*v0.w;
        vacc[4] += a*v1.x; vacc[5] += a*v1.y; vacc[6] += a*v1.z; vacc[7] += a*v1.w;
        tacc[0] += a*a0.x; tacc[1] += a*a0.y; tacc[2] += a*a0.z; tacc[3] += a*a0.w;
        tacc[4] += a*a1.x; tacc[5] += a*a1.y; tacc[6] += a*a1.z; tacc[7] += a*a1.w;
    }
    // head-reduce v: lane L holds col512 = L*8+i -> cc = (L&7)*8+i, head = L>>3.
    // xor over {8,16,32} sums across heads for fixed (L&7, i).
    #pragma unroll
    for (int i = 0; i < 8; ++i) {
        vacc[i] += __shfl_xor(vacc[i], 8);
        vacc[i] += __shfl_xor(vacc[i], 16);
        vacc[i] += __shfl_xor(vacc[i], 32);
    }
    float4 o;
    if (lane < 8) {
        o = {vacc[0],vacc[1],vacc[2],vacc[3]}; *(float4*)(vsum + (size_t)n*64 + lane*8)     = o;
        o = {vacc[4],vacc[5],vacc[6],vacc[7]}; *(float4*)(vsum + (size_t)n*64 + lane*8 + 4) = o;
    }
    o = {tacc[0],tacc[1],tacc[2],tacc[3]}; *(float4*)(tbuf + (size_t)n*512 + lane*8)     = o;
    o = {tacc[4],tacc[5],tacc[6],tacc[7]}; *(float4*)(tbuf + (size_t)n*512 + lane*8 + 4) = o;
    if (p == 0) sbuf[(size_t)n*8 + h] = sacc;
}

// hnext = relu( vsum + tbuf@We' + (sbuf·be-blocks) + hin@Ws + bs ),
// We'[h*64+j][cc] = We[j][h*64+cc].  Tiled GEMM: BM=64, 9 LDS stages.
__global__ void __launch_bounds__(256) k_node_finish(
    const float* __restrict__ vsum, const float* __restrict__ tbuf, const float* __restrict__ sbuf,
    const float* __restrict__ hin, const float* __restrict__ We, const float* __restrict__ be,
    const float* __restrict__ Ws, const float* __restrict__ bs,
    float* __restrict__ hnext, int N)
{
    __shared__ __align__(16) float At[64][64];
    __shared__ __align__(16) float Bt[64][64];
    int tid = threadIdx.x;
    int wv = tid >> 6, lane = tid & 63;
    int n0 = blockIdx.x * 64;
    float acc[16];
    float bsv = bs[lane];
    #pragma unroll
    for (int r = 0; r < 16; ++r) {
        int n = n0 + wv*16 + r;
        float a = bsv;
        if (n < N) {
            a += vsum[(size_t)n*64 + lane];
            #pragma unroll
            for (int h = 0; h < 8; ++h) a += sbuf[(size_t)n*8 + h] * be[h*64 + lane];
        }
        acc[r] = a;
    }
    for (int st = 0; st < 9; ++st) {
        __syncthreads();
        if (st < 8) {
            for (int i = tid; i < 4096; i += 256) {
                int r = i >> 6, c = i & 63;
                int n = n0 + r;
                At[r][c] = (n < N) ? tbuf[(size_t)n*512 + st*64 + c] : 0.f;
                Bt[r][c] = We[(size_t)r*512 + st*64 + c];
            }
        } else {
            for (int i = tid; i < 4096; i += 256) {
                int r = i >> 6, c = i & 63;
                int n = n0 + r;
                At[r][c] = (n < N) ? hin[(size_t)n*64 + c] : 0.f;
                Bt[r][c] = Ws[(size_t)r*64 + c];
            }
        }
        __syncthreads();
        #pragma unroll 4
        for (int j = 0; j < 64; ++j) {
            float w = Bt[j][lane];
            #pragma unroll
            for (int r = 0; r < 16; ++r) acc[r] += At[wv*16 + r][j] * w;
        }
    }
    #pragma unroll
    for (int r = 0; r < 16; ++r) {
        int n = n0 + wv*16 + r;
        if (n < N) hnext[(size_t)n*64 + lane] = fmaxf(acc[r], 0.f);
    }
}

// ea2 = relu([h[src], h[dst], ea] @ euW + eub)  (192x64)
__global__ void __launch_bounds__(256) k_edge_update(
    const float* __restrict__ h, const float* __restrict__ ea,
    const float* __restrict__ euW, const float* __restrict__ eub,
    const int* __restrict__ src, const int* __restrict__ dst,
    float* __restrict__ ea2, int E)
{
    __shared__ __align__(16) float s_src[32][64];
    __shared__ __align__(16) float s_dst[32][64];
    __shared__ __align__(16) float s_ea[32][64];
    __shared__ int sid[32], did[32];
    int tid = threadIdx.x;
    int e0 = blockIdx.x * 32;
    if (tid < 32) {
        int e = e0 + tid; if (e >= E) e = E - 1;
        sid[tid] = src[e]; did[tid] = dst[e];
    }
    __syncthreads();
    for (int i = tid; i < 2048; i += 256) {
        int r = i >> 6, c = i & 63;
        int e = e0 + r; if (e >= E) e = E - 1;
        s_src[r][c] = h[(size_t)sid[r]*64 + c];
        s_dst[r][c] = h[(size_t)did[r]*64 + c];
        s_ea[r][c]  = ea[(size_t)e*64 + c];
    }
    __syncthreads();
    int wv = tid >> 6, lane = tid & 63;
    float acc[8];
    float bv = eub[lane];
    #pragma unroll
    for (int t = 0; t < 8; ++t) acc[t] = bv;
    #pragma unroll 4
    for (int j = 0; j < 64; ++j) {
        float wval = euW[(size_t)j*64 + lane];
        #pragma unroll
        for (int t = 0; t < 8; ++t) acc[t] += s_src[wv*8 + t][j] * wval;
    }
    #pragma unroll 4
    for (int j = 0; j < 64; ++j) {
        float wval = euW[(size_t)(64 + j)*64 + lane];
        #pragma unroll
        for (int t = 0; t < 8; ++t) acc[t] += s_dst[wv*8 + t][j] * wval;
    }
    #pragma unroll 4
    for (int j = 0; j < 64; ++j) {
        float wval = euW[(size_t)(128 + j)*64 + lane];
        #pragma unroll
        for (int t = 0; t < 8; ++t) acc[t] += s_ea[wv*8 + t][j] * wval;
    }
    #pragma unroll
    for (int t = 0; t < 8; ++t) {
        int e = e0 + wv*8 + t;
        if (e < E) ea2[(size_t)e*64 + lane] = fmaxf(acc[t], 0.f);
    }
}

// ---------------- pooling / head ----------------

__global__ void __launch_bounds__(64) k_node_pool(
    const float* __restrict__ h, const int* __restrict__ batch,
    float* __restrict__ npool, float* __restrict__ cn, int N)
{
    int lane = threadIdx.x;
    int n0 = blockIdx.x * 64;
    float acc = 0.f; int cur = -1; int run = 0;
    for (int i = 0; i < 64; ++i) {
        int n = n0 + i;
        if (n >= N) break;
        int b = batch[n];
        if (b != cur) {
            if (cur >= 0) {
                atomicAdd(npool + (size_t)cur*64 + lane, acc);
                if (lane == 0) atomicAdd(cn + cur, (float)run);
            }
            cur = b; acc = 0.f; run = 0;
        }
        acc += h[(size_t)n*64 + lane];
        ++run;
    }
    if (cur >= 0) {
        atomicAdd(npool + (size_t)cur*64 + lane, acc);
        if (lane == 0) atomicAdd(cn + cur, (float)run);
    }
}

__global__ void __launch_bounds__(256) k_edge_pool(
    const float* __restrict__ ea, const int* __restrict__ src, const int* __restrict__ batch,
    float* __restrict__ epool, float* __restrict__ ce, int E)
{
    __shared__ float pool_s[32][64];
    __shared__ float cnt_s[32];
    int tid = threadIdx.x;
    for (int i = tid; i < 2048; i += 256) ((float*)pool_s)[i] = 0.f;
    if (tid < 32) cnt_s[tid] = 0.f;
    __syncthreads();
    int wv = tid >> 6, lane = tid & 63;
    int base = blockIdx.x * 256 + wv * 64;
    #pragma unroll 4
    for (int i = 0; i < 64; ++i) {
        int e = base + i;
        if (e < E) {
            int b = batch[src[e]];
            float val = ea[(size_t)e*64 + lane];
            atomicAdd(&pool_s[b][lane], val);
            if (lane == 0) atomicAdd(&cnt_s[b], 1.f);
        }
    }
    __syncthreads();
    for (int i = tid; i < 2048; i += 256) atomicAdd(epool + i, ((float*)pool_s)[i]);
    if (tid < 32) atomicAdd(ce + tid, cnt_s[tid]);
}

__global__ void __launch_bounds__(64) k_head_mlp(
    const float* __restrict__ npool, const float* __restrict__ epool,
    const float* __restrict__ cn, const float* __restrict__ ce,
    const float* __restrict__ rW1, const float* __restrict__ rb1,
    const float* __restrict__ rW2, const float* __restrict__ rb2,
    const float* __restrict__ rW3, const float* __restrict__ rb3,
    float* __restrict__ out)
{
    __shared__ float g[128];
    __shared__ float h1[64];
    __shared__ float h2[64];
    int b = blockIdx.x, lane = threadIdx.x;
    float cnv = fmaxf(cn[b], 1.f), cev = fmaxf(ce[b], 1.f);
    g[lane]      = npool[(size_t)b*64 + lane] / cnv;
    g[64 + lane] = epool[(size_t)b*64 + lane] / cev;
    __syncthreads();
    float acc = rb1[lane];
    #pragma unroll 4
    for (int j = 0; j < 128; ++j) acc += g[j] * rW1[j*64 + lane];
    h1[lane] = fmaxf(acc, 0.f);
    __syncthreads();
    acc = rb2[lane];
    #pragma unroll 4
    for (int j = 0; j < 64; ++j) acc += h1[j] * rW2[j*64 + lane];
    h2[lane] = fmaxf(acc, 0.f);
    __syncthreads();
    if (lane < 2) {
        float o = rb3[lane];
        for (int j = 0; j < 64; ++j) o += h2[j] * rW3[j*2 + lane];
        out[b*2 + lane] = tanhf(o);
    }
}

// ---------------- launcher ----------------

extern "C" void kernel_launch(void* const* d_in, const int* in_sizes, int n_in,
                              void* d_out, int out_size, void* d_ws, size_t ws_size,
                              hipStream_t stream)
{
    const float* x         = (const float*)d_in[0];
    const float* edge_attr = (const float*)d_in[1];
    const float* means     = (const float*)d_in[2];
    const float* log_stds  = (const float*)d_in[3];
    const float* spW       = (const float*)d_in[4];
    const float* spb       = (const float*)d_in[5];
    const float* neW       = (const float*)d_in[6];
    const float* neb       = (const float*)d_in[7];
    const float* eeW       = (const float*)d_in[8];
    const float* eeb       = (const float*)d_in[9];
    const float* Wq        = (const float*)d_in[10];
    const float* bq        = (const float*)d_in[11];
    const float* Wk        = (const float*)d_in[12];
    const float* bk        = (const float*)d_in[13];
    const float* Wv        = (const float*)d_in[14];
    const float* bv        = (const float*)d_in[15];
    const float* We        = (const float*)d_in[16];
    const float* be        = (const float*)d_in[17];
    const float* Ws        = (const float*)d_in[18];
    const float* bs        = (const float*)d_in[19];
    const float* euW       = (const float*)d_in[20];
    const float* eub       = (const float*)d_in[21];
    const float* rW1       = (const float*)d_in[22];
    const float* rb1       = (const float*)d_in[23];
    const float* rW2       = (const float*)d_in[24];
    const float* rb2       = (const float*)d_in[25];
    const float* rW3       = (const float*)d_in[26];
    const float* rb3       = (const float*)d_in[27];
    const int* eidx        = (const int*)d_in[28];
    const int* batch       = (const int*)d_in[29];

    int N = in_sizes[0] / 7;
    int E = in_sizes[1] / 4;
    const int G = 32;
    const int* srcp = eidx;
    const int* dstp = eidx + E;

    float* ws = (float*)d_ws;
    size_t fl = 0;
    float* hA    = ws + fl; fl += (size_t)N * 64;
    float* hB    = ws + fl; fl += (size_t)N * 64;
    float* eaA   = ws + fl; fl += (size_t)E * 64;
    float* eaB   = ws + fl; fl += (size_t)E * 64;
    float* B1    = ws + fl; fl += (size_t)N * 512;   // q, then v
    float* B2    = ws + fl; fl += (size_t)N * 512;   // k, then vsum (N*64)
    float* B3    = ws + fl; fl += (size_t)N * 512;   // qe, then tbuf
    float* alpha = ws + fl; fl += (size_t)E * 8;     // also wbuf (E*4) at init
    float* mbuf  = ws + fl; fl += (size_t)N * 8;
    float* dbuf  = ws + fl; fl += (size_t)N * 8;
    float* sbuf  = ws + fl; fl += (size_t)N * 8;
    float* npool = ws + fl; fl += (size_t)G * 64;
    float* epool = ws + fl; fl += (size_t)G * 64;
    float* cn    = ws + fl; fl += G;
    float* ce    = ws + fl; fl += G;
    int* ideg  = (int*)(ws + fl); fl += (size_t)N;
    int* iptr  = (int*)(ws + fl); fl += (size_t)N + 1;
    int* ihead = (int*)(ws + fl); fl += (size_t)N;
    int* iperm = (int*)(ws + fl); fl += (size_t)E;
    // total ~47.5M floats = 190.1 MB (ws known >= 194 MB from round 1)

    float* wbuf = alpha;   // E*4 <= E*8, dead before alpha is first written

    hipMemsetAsync(npool, 0, (size_t)(G * 130) * sizeof(float), stream);
    hipMemsetAsync(ideg, 0, (size_t)N * sizeof(int), stream);

    k_node_embed<<<(N * 64 + 255) / 256, 256, 0, stream>>>(x, neW, neb, hA, N);
    k_edge_w<<<(E + 255) / 256, 256, 0, stream>>>(x, means, log_stds, srcp, dstp, wbuf, E);
    k_edge_ea<<<((size_t)E * 64 + 255) / 256, 256, 0, stream>>>(edge_attr, wbuf,
                                                                spW, spb, eeW, eeb, eaA, E);
    k_hist<<<(E + 255) / 256, 256, 0, stream>>>(dstp, ideg, E);
    k_scan<<<1, 1024, 0, stream>>>(ideg, iptr, ihead, N);
    k_scatter<<<(E + 255) / 256, 256, 0, stream>>>(dstp, ihead, iperm, E);

    float* hcur = hA;  float* hnext = hB;
    float* eacur = eaA; float* eanext = eaB;
    for (int l = 0; l < 3; ++l) {
        const float* Wq_l = Wq + (size_t)l * 64 * 512;
        const float* Wk_l = Wk + (size_t)l * 64 * 512;
        const float* Wv_l = Wv + (size_t)l * 64 * 512;
        const float* We_l = We + (size_t)l * 64 * 512;
        const float* be_l = be + (size_t)l * 512;

        k_gemm512_r32<<<(N + 31) / 32, 256, 0, stream>>>(hcur, Wq_l, bq + (size_t)l * 512, B1, N);
        k_gemm512_r32<<<(N + 31) / 32, 256, 0, stream>>>(hcur, Wk_l, bk + (size_t)l * 512, B2, N);
        k_qe<<<dim3((N + 31) / 32, 8), 256, 0, stream>>>(B1, We_l, B3, N);
        k_attn_alpha<<<(N + 3) / 4, 256, 0, stream>>>(B1, B2, B3, be_l, eacur,
                                                      iptr, iperm, srcp, alpha, mbuf, dbuf, N);
        k_gemm512_r32<<<(N + 31) / 32, 256, 0, stream>>>(hcur, Wv_l, bv + (size_t)l * 512, B1, N);
        k_attn_agg<<<(N + 3) / 4, 256, 0, stream>>>(alpha, mbuf, dbuf, B1, eacur,
                                                    iptr, iperm, srcp, B2, B3, sbuf, N);
        k_node_finish<<<(N + 63) / 64, 256, 0, stream>>>(B2, B3, sbuf, hcur, We_l, be_l,
                                                         Ws + (size_t)l * 64 * 64,
                                                         bs + (size_t)l * 64, hnext, N);
        k_edge_update<<<(E + 31) / 32, 256, 0, stream>>>(hnext, eacur, euW + (size_t)l * 192 * 64,
                                                         eub + (size_t)l * 64, srcp, dstp, eanext, E);
        float* t1 = hcur; hcur = hnext; hnext = t1;
        float* t2 = eacur; eacur = eanext; eanext = t2;
    }

    k_node_pool<<<(N + 63) / 64, 64, 0, stream>>>(hcur, batch, npool, cn, N);
    k_edge_pool<<<(E + 255) / 256, 256, 0, stream>>>(eacur, srcp, batch, epool, ce, E);
    k_head_mlp<<<G, 64, 0, stream>>>(npool, epool, cn, ce, rW1, rb1, rW2, rb2, rW3, rb3,
                                     (float*)d_out);
}

// Round 6
// 1219.623 us; speedup vs baseline: 1.1384x; 1.1384x over previous
//
#include <hip/hip_runtime.h>
#include <hip/hip_bf16.h>
#include <cstdint>
#include <cstddef>

// N=20000, E=100000, G=32, HID=64, HEADS=8, HC=64, HO=512, L=3, K=4. All fp32.
// e = ea@We+be only appears inside q·(k+e) and Σ a(v+e):
//   q·e|_h = ea · qe[dst]|_h,  qe[d][h*64+j] = Σ_c q[d][64h+c] We[j][64h+c]
//   Σ a e  = (Σ a ea) @ We + (Σ a) be   -> all We GEMMs at N-level.
// R5 lesson: BM=64 single-kernel node_finish had grid=313 blocks -> 13% occupancy,
// latency-bound. R6: split K into 9 grid-y partials (tbuf head-blocks + hin@Ws),
// 2817 blocks, then a streaming reduce. Partials alias B1 (dead v) + B2 tail.

// ---------------- embed / init ----------------

__global__ void __launch_bounds__(256) k_node_embed(
    const float* __restrict__ x, const float* __restrict__ neW, const float* __restrict__ neb,
    float* __restrict__ h, int N)
{
    int idx = blockIdx.x * 256 + threadIdx.x;
    int n = idx >> 6, c = idx & 63;
    if (n >= N) return;
    float acc = neb[c];
    #pragma unroll
    for (int j = 0; j < 7; ++j) acc += x[(size_t)n * 7 + j] * neW[j * 64 + c];
    h[(size_t)n * 64 + c] = fmaxf(acc, 0.f);
}

__global__ void __launch_bounds__(256) k_edge_w(
    const float* __restrict__ x,
    const float* __restrict__ means, const float* __restrict__ log_stds,
    const int* __restrict__ src, const int* __restrict__ dst,
    float* __restrict__ wbuf, int E)
{
    int e = blockIdx.x * 256 + threadIdx.x;
    if (e >= E) return;
    int s = src[e], d = dst[e];
    const float* ps = x + (size_t)s * 7;
    const float* pd = x + (size_t)d * 7;
    float slx = ps[0], sly = ps[1], srx = ps[2], sry = ps[3];
    float dlx = pd[0], dly = pd[1], drx = pd[2], dry = pd[3];
    float u[8];
    float rx, ry;
    rx = dlx - slx; ry = dly - sly; u[0] = sqrtf(rx*rx + ry*ry); u[1] = atan2f(ry, rx);
    rx = dlx - srx; ry = dly - sry; u[2] = sqrtf(rx*rx + ry*ry); u[3] = atan2f(ry, rx);
    rx = drx - slx; ry = dry - sly; u[4] = sqrtf(rx*rx + ry*ry); u[5] = atan2f(ry, rx);
    rx = drx - srx; ry = dry - sry; u[6] = sqrtf(rx*rx + ry*ry); u[7] = atan2f(ry, rx);
    #pragma unroll
    for (int kk = 0; kk < 4; ++kk) {
        float ssum = 0.f;
        #pragma unroll
        for (int dd = 0; dd < 8; ++dd) {
            float stdv = expf(log_stds[kk*8+dd]) + 1e-6f;
            float z = (u[dd] - means[kk*8+dd]) / stdv;
            ssum += z * z;
        }
        wbuf[(size_t)e*4 + kk] = expf(-0.5f * ssum);
    }
}

__global__ void __launch_bounds__(256) k_edge_ea(
    const float* __restrict__ edge_attr, const float* __restrict__ wbuf,
    const float* __restrict__ spW, const float* __restrict__ spb,
    const float* __restrict__ eeW, const float* __restrict__ eeb,
    float* __restrict__ ea, int E)
{
    int idx = blockIdx.x * 256 + threadIdx.x;
    int e = idx >> 6, c = idx & 63;
    if (e >= E) return;
    float acce = eeb[c];
    #pragma unroll
    for (int j = 0; j < 4; ++j) acce += edge_attr[(size_t)e*4 + j] * eeW[j*64 + c];
    float accs = spb[c];
    #pragma unroll
    for (int j = 0; j < 4; ++j) accs += wbuf[(size_t)e*4 + j] * spW[j*64 + c];
    ea[(size_t)e*64 + c] = fmaxf(acce, 0.f) + fmaxf(accs, 0.f);
}

// ---------------- CSR build ----------------

__global__ void __launch_bounds__(256) k_hist(
    const int* __restrict__ dst, int* __restrict__ deg, int E)
{
    int e = blockIdx.x * 256 + threadIdx.x;
    if (e < E) atomicAdd(deg + dst[e], 1);
}

__global__ void __launch_bounds__(1024) k_scan(
    const int* __restrict__ deg, int* __restrict__ ptr, int* __restrict__ headw, int N)
{
    __shared__ int part[1024];
    int t = threadIdx.x;
    int per = (N + 1023) / 1024;
    int s = 0;
    for (int i = 0; i < per; ++i) { int idx = t*per + i; if (idx < N) s += deg[idx]; }
    part[t] = s;
    __syncthreads();
    for (int off = 1; off < 1024; off <<= 1) {
        int v = (t >= off) ? part[t - off] : 0;
        __syncthreads();
        part[t] += v;
        __syncthreads();
    }
    int base = (t > 0) ? part[t - 1] : 0;
    for (int i = 0; i < per; ++i) {
        int idx = t*per + i;
        if (idx < N) { ptr[idx] = base; headw[idx] = base; base += deg[idx]; }
    }
    if (t == 1023) ptr[N] = part[1023];
}

__global__ void __launch_bounds__(256) k_scatter(
    const int* __restrict__ dst, int* __restrict__ headw, int* __restrict__ perm, int E)
{
    int e = blockIdx.x * 256 + threadIdx.x;
    if (e < E) {
        int pos = atomicAdd(headw + dst[e], 1);
        perm[pos] = e;
    }
}

// ---------------- GEMMs ----------------

__global__ void __launch_bounds__(256) k_gemm512_r32(
    const float* __restrict__ X, const float* __restrict__ W, const float* __restrict__ bias,
    float* __restrict__ Y, int M)
{
    __shared__ __align__(16) float xs[32][64];
    int tid = threadIdx.x;
    int r0 = blockIdx.x * 32;
    for (int i = tid; i < 2048; i += 256) {
        int r = i >> 6, c = i & 63;
        int rr = r0 + r;
        xs[r][c] = (rr < M) ? X[(size_t)rr * 64 + c] : 0.f;
    }
    __syncthreads();
    int wv = tid >> 6, lane = tid & 63;
    int c0 = lane * 8;
    float acc[8][8];
    float4 b0 = *(const float4*)(bias + c0);
    float4 b1 = *(const float4*)(bias + c0 + 4);
    #pragma unroll
    for (int t = 0; t < 8; ++t) {
        acc[t][0]=b0.x; acc[t][1]=b0.y; acc[t][2]=b0.z; acc[t][3]=b0.w;
        acc[t][4]=b1.x; acc[t][5]=b1.y; acc[t][6]=b1.z; acc[t][7]=b1.w;
    }
    #pragma unroll 2
    for (int j = 0; j < 64; ++j) {
        float4 wa = *(const float4*)(W + (size_t)j*512 + c0);
        float4 wb = *(const float4*)(W + (size_t)j*512 + c0 + 4);
        #pragma unroll
        for (int t = 0; t < 8; ++t) {
            float a = xs[wv*8 + t][j];
            acc[t][0] += a*wa.x; acc[t][1] += a*wa.y; acc[t][2] += a*wa.z; acc[t][3] += a*wa.w;
            acc[t][4] += a*wb.x; acc[t][5] += a*wb.y; acc[t][6] += a*wb.z; acc[t][7] += a*wb.w;
        }
    }
    #pragma unroll
    for (int t = 0; t < 8; ++t) {
        int r = r0 + wv*8 + t;
        if (r < M) {
            float4 o0 = {acc[t][0],acc[t][1],acc[t][2],acc[t][3]};
            float4 o1 = {acc[t][4],acc[t][5],acc[t][6],acc[t][7]};
            *(float4*)(Y + (size_t)r*512 + c0)     = o0;
            *(float4*)(Y + (size_t)r*512 + c0 + 4) = o1;
        }
    }
}

// qe[d][h*64+j] = sum_c q[d][64h+c] * We[j][64h+c].  grid: ((N+31)/32, 8)
__global__ void __launch_bounds__(256) k_qe(
    const float* __restrict__ q, const float* __restrict__ We,
    float* __restrict__ qe, int N)
{
    __shared__ __align__(16) float qlds[32][64];
    __shared__ float welds[64][65];
    int tid = threadIdx.x;
    int h = blockIdx.y;
    int n0 = blockIdx.x * 32;
    for (int i = tid; i < 2048; i += 256) {
        int r = i >> 6, c = i & 63;
        int n = n0 + r;
        qlds[r][c] = (n < N) ? q[(size_t)n*512 + h*64 + c] : 0.f;
    }
    for (int i = tid; i < 4096; i += 256) {
        int j = i >> 6, c = i & 63;
        welds[j][c] = We[(size_t)j*512 + h*64 + c];
    }
    __syncthreads();
    int wv = tid >> 6, lane = tid & 63;   // lane = j
    float acc[8];
    #pragma unroll
    for (int r = 0; r < 8; ++r) acc[r] = 0.f;
    #pragma unroll 4
    for (int c = 0; c < 64; ++c) {
        float w = welds[lane][c];
        #pragma unroll
        for (int r = 0; r < 8; ++r) acc[r] += qlds[wv*8 + r][c] * w;
    }
    #pragma unroll
    for (int r = 0; r < 8; ++r) {
        int n = n0 + wv*8 + r;
        if (n < N) qe[(size_t)n*512 + h*64 + lane] = acc[r];
    }
}

// ---------------- CSR-fused attention ----------------

__global__ void __launch_bounds__(256) k_attn_alpha(
    const float* __restrict__ q, const float* __restrict__ k, const float* __restrict__ qe,
    const float* __restrict__ be, const float* __restrict__ ea,
    const int* __restrict__ ptr, const int* __restrict__ perm, const int* __restrict__ srcp,
    float* __restrict__ alpha, float* __restrict__ mbuf, float* __restrict__ dbuf, int N)
{
    int wv = threadIdx.x >> 6, lane = threadIdx.x & 63;
    int n = blockIdx.x * 4 + wv;
    if (n >= N) return;
    int h = lane >> 3, p = lane & 7;
    int b = ptr[n], e_ = ptr[n + 1];
    const float4* qp = (const float4*)(q + (size_t)n*512 + lane*8);
    float4 q0 = qp[0], q1 = qp[1];
    const float4* qep = (const float4*)(qe + (size_t)n*512 + lane*8);
    float4 g0 = qep[0], g1 = qep[1];
    const float4* bep = (const float4*)(be + lane*8);
    float4 b0 = bep[0], b1 = bep[1];
    float qbe = q0.x*b0.x + q0.y*b0.y + q0.z*b0.z + q0.w*b0.w
              + q1.x*b1.x + q1.y*b1.y + q1.z*b1.z + q1.w*b1.w;
    qbe += __shfl_xor(qbe, 1);
    qbe += __shfl_xor(qbe, 2);
    qbe += __shfl_xor(qbe, 4);
    float m = -3.4e38f, den = 0.f;
    for (int it = b; it < e_; ++it) {
        int e = perm[it];
        int s = srcp[e];
        const float4* kp = (const float4*)(k + (size_t)s*512 + lane*8);
        float4 k0 = kp[0], k1 = kp[1];
        const float4* ap = (const float4*)(ea + (size_t)e*64 + p*8);
        float4 a0 = ap[0], a1 = ap[1];
        float t = q0.x*k0.x + q0.y*k0.y + q0.z*k0.z + q0.w*k0.w
                + q1.x*k1.x + q1.y*k1.y + q1.z*k1.z + q1.w*k1.w
                + a0.x*g0.x + a0.y*g0.y + a0.z*g0.z + a0.w*g0.w
                + a1.x*g1.x + a1.y*g1.y + a1.z*g1.z + a1.w*g1.w;
        t += __shfl_xor(t, 1);
        t += __shfl_xor(t, 2);
        t += __shfl_xor(t, 4);
        float al = 0.125f * (t + qbe);
        float mn = fmaxf(m, al);
        den = den * expf(m - mn) + expf(al - mn);
        m = mn;
        if (p == 0) alpha[(size_t)e*8 + h] = al;
    }
    if (p == 0) {
        mbuf[(size_t)n*8 + h] = m;
        dbuf[(size_t)n*8 + h] = den;
    }
}

// vsum[n][cc] = Σ_h Σ_e a v[s][64h+cc] (head-reduced in-register via shfl);
// tbuf[n][h*64+j] = Σ a_h ea[j]; sbuf[n][h] = Σ a_h.
__global__ void __launch_bounds__(256) k_attn_agg(
    const float* __restrict__ alpha, const float* __restrict__ mbuf, const float* __restrict__ dbuf,
    const float* __restrict__ v, const float* __restrict__ ea,
    const int* __restrict__ ptr, const int* __restrict__ perm, const int* __restrict__ srcp,
    float* __restrict__ vsum, float* __restrict__ tbuf, float* __restrict__ sbuf, int N)
{
    int wv = threadIdx.x >> 6, lane = threadIdx.x & 63;
    int n = blockIdx.x * 4 + wv;
    if (n >= N) return;
    int h = lane >> 3, p = lane & 7;
    int b = ptr[n], e_ = ptr[n + 1];
    float m = mbuf[(size_t)n*8 + h];
    float inv = 0.125f / (dbuf[(size_t)n*8 + h] + 1e-16f);   // 1/HEADS folded in
    float vacc[8], tacc[8];
    #pragma unroll
    for (int i = 0; i < 8; ++i) { vacc[i] = 0.f; tacc[i] = 0.f; }
    float sacc = 0.f;
    for (int it = b; it < e_; ++it) {
        int e = perm[it];
        int s = srcp[e];
        float a = expf(alpha[(size_t)e*8 + h] - m) * inv;
        sacc += a;
        const float4* vp = (const float4*)(v + (size_t)s*512 + lane*8);
        float4 v0 = vp[0], v1 = vp[1];
        const float4* ap = (const float4*)(ea + (size_t)e*64 + p*8);
        float4 a0 = ap[0], a1 = ap[1];
        vacc[0] += a*v0.x; vacc[1] += a*v0.y; vacc[2] += a*v0.z; vacc[3] += a*v0.w;
        vacc[4] += a*v1.x; vacc[5] += a*v1.y; vacc[6] += a*v1.z; vacc[7] += a*v1.w;
        tacc[0] += a*a0.x; tacc[1] += a*a0.y; tacc[2] += a*a0.z; tacc[3] += a*a0.w;
        tacc[4] += a*a1.x; tacc[5] += a*a1.y; tacc[6] += a*a1.z; tacc[7] += a*a1.w;
    }
    #pragma unroll
    for (int i = 0; i < 8; ++i) {
        vacc[i] += __shfl_xor(vacc[i], 8);
        vacc[i] += __shfl_xor(vacc[i], 16);
        vacc[i] += __shfl_xor(vacc[i], 32);
    }
    float4 o;
    if (lane < 8) {
        o = {vacc[0],vacc[1],vacc[2],vacc[3]}; *(float4*)(vsum + (size_t)n*64 + lane*8)     = o;
        o = {vacc[4],vacc[5],vacc[6],vacc[7]}; *(float4*)(vsum + (size_t)n*64 + lane*8 + 4) = o;
    }
    o = {tacc[0],tacc[1],tacc[2],tacc[3]}; *(float4*)(tbuf + (size_t)n*512 + lane*8)     = o;
    o = {tacc[4],tacc[5],tacc[6],tacc[7]}; *(float4*)(tbuf + (size_t)n*512 + lane*8 + 4) = o;
    if (p == 0) sbuf[(size_t)n*8 + h] = sacc;
}

// Partial GEMM, grid (ceil(N/64), 9):
//  st<8: pbuf0[st][n][cc] = Σ_j tbuf[n][st*64+j] * We[j][st*64+cc]
//  st=8: pbuf8[n][cc]     = Σ_j hin[n][j]       * Ws[j][cc]
__global__ void __launch_bounds__(256) k_nf_gemm(
    const float* __restrict__ tbuf, const float* __restrict__ hin,
    const float* __restrict__ We, const float* __restrict__ Ws,
    float* __restrict__ pbuf0, float* __restrict__ pbuf8, int N)
{
    __shared__ __align__(16) float At[64][64];
    __shared__ __align__(16) float Bt[64][64];
    int tid = threadIdx.x;
    int st = blockIdx.y;
    int n0 = blockIdx.x * 64;
    if (st < 8) {
        for (int i = tid; i < 4096; i += 256) {
            int r = i >> 6, c = i & 63;
            int n = n0 + r;
            At[r][c] = (n < N) ? tbuf[(size_t)n*512 + st*64 + c] : 0.f;
            Bt[r][c] = We[(size_t)r*512 + st*64 + c];
        }
    } else {
        for (int i = tid; i < 4096; i += 256) {
            int r = i >> 6, c = i & 63;
            int n = n0 + r;
            At[r][c] = (n < N) ? hin[(size_t)n*64 + c] : 0.f;
            Bt[r][c] = Ws[(size_t)r*64 + c];
        }
    }
    __syncthreads();
    int wv = tid >> 6, lane = tid & 63;
    float acc[16];
    #pragma unroll
    for (int r = 0; r < 16; ++r) acc[r] = 0.f;
    #pragma unroll 4
    for (int j = 0; j < 64; ++j) {
        float w = Bt[j][lane];
        #pragma unroll
        for (int r = 0; r < 16; ++r) acc[r] += At[wv*16 + r][j] * w;
    }
    float* out = (st < 8) ? (pbuf0 + (size_t)st * N * 64) : pbuf8;
    #pragma unroll
    for (int r = 0; r < 16; ++r) {
        int n = n0 + wv*16 + r;
        if (n < N) out[(size_t)n*64 + lane] = acc[r];
    }
}

// hnext = relu( vsum + Σ_st pbuf + pbuf8 + Σ_h sbuf·be + bs )
__global__ void __launch_bounds__(256) k_nf_reduce(
    const float* __restrict__ vsum, const float* __restrict__ pbuf0,
    const float* __restrict__ pbuf8, const float* __restrict__ sbuf,
    const float* __restrict__ be, const float* __restrict__ bs,
    float* __restrict__ hnext, int N)
{
    int idx = blockIdx.x * 256 + threadIdx.x;
    int n = idx >> 6, cc = idx & 63;
    if (n >= N) return;
    float a = bs[cc] + vsum[(size_t)n*64 + cc] + pbuf8[(size_t)n*64 + cc];
    #pragma unroll
    for (int st = 0; st < 8; ++st) a += pbuf0[(size_t)st*N*64 + (size_t)n*64 + cc];
    #pragma unroll
    for (int h = 0; h < 8; ++h) a += sbuf[(size_t)n*8 + h] * be[h*64 + cc];
    hnext[(size_t)n*64 + cc] = fmaxf(a, 0.f);
}

// ea2 = relu([h[src], h[dst], ea] @ euW + eub)  (192x64)
__global__ void __launch_bounds__(256) k_edge_update(
    const float* __restrict__ h, const float* __restrict__ ea,
    const float* __restrict__ euW, const float* __restrict__ eub,
    const int* __restrict__ src, const int* __restrict__ dst,
    float* __restrict__ ea2, int E)
{
    __shared__ __align__(16) float s_src[32][64];
    __shared__ __align__(16) float s_dst[32][64];
    __shared__ __align__(16) float s_ea[32][64];
    __shared__ int sid[32], did[32];
    int tid = threadIdx.x;
    int e0 = blockIdx.x * 32;
    if (tid < 32) {
        int e = e0 + tid; if (e >= E) e = E - 1;
        sid[tid] = src[e]; did[tid] = dst[e];
    }
    __syncthreads();
    for (int i = tid; i < 2048; i += 256) {
        int r = i >> 6, c = i & 63;
        int e = e0 + r; if (e >= E) e = E - 1;
        s_src[r][c] = h[(size_t)sid[r]*64 + c];
        s_dst[r][c] = h[(size_t)did[r]*64 + c];
        s_ea[r][c]  = ea[(size_t)e*64 + c];
    }
    __syncthreads();
    int wv = tid >> 6, lane = tid & 63;
    float acc[8];
    float bv = eub[lane];
    #pragma unroll
    for (int t = 0; t < 8; ++t) acc[t] = bv;
    #pragma unroll 4
    for (int j = 0; j < 64; ++j) {
        float wval = euW[(size_t)j*64 + lane];
        #pragma unroll
        for (int t = 0; t < 8; ++t) acc[t] += s_src[wv*8 + t][j] * wval;
    }
    #pragma unroll 4
    for (int j = 0; j < 64; ++j) {
        float wval = euW[(size_t)(64 + j)*64 + lane];
        #pragma unroll
        for (int t = 0; t < 8; ++t) acc[t] += s_dst[wv*8 + t][j] * wval;
    }
    #pragma unroll 4
    for (int j = 0; j < 64; ++j) {
        float wval = euW[(size_t)(128 + j)*64 + lane];
        #pragma unroll
        for (int t = 0; t < 8; ++t) acc[t] += s_ea[wv*8 + t][j] * wval;
    }
    #pragma unroll
    for (int t = 0; t < 8; ++t) {
        int e = e0 + wv*8 + t;
        if (e < E) ea2[(size_t)e*64 + lane] = fmaxf(acc[t], 0.f);
    }
}

// ---------------- pooling / head ----------------

__global__ void __launch_bounds__(64) k_node_pool(
    const float* __restrict__ h, const int* __restrict__ batch,
    float* __restrict__ npool, float* __restrict__ cn, int N)
{
    int lane = threadIdx.x;
    int n0 = blockIdx.x * 64;
    float acc = 0.f; int cur = -1; int run = 0;
    for (int i = 0; i < 64; ++i) {
        int n = n0 + i;
        if (n >= N) break;
        int b = batch[n];
        if (b != cur) {
            if (cur >= 0) {
                atomicAdd(npool + (size_t)cur*64 + lane, acc);
                if (lane == 0) atomicAdd(cn + cur, (float)run);
            }
            cur = b; acc = 0.f; run = 0;
        }
        acc += h[(size_t)n*64 + lane];
        ++run;
    }
    if (cur >= 0) {
        atomicAdd(npool + (size_t)cur*64 + lane, acc);
        if (lane == 0) atomicAdd(cn + cur, (float)run);
    }
}

__global__ void __launch_bounds__(256) k_edge_pool(
    const float* __restrict__ ea, const int* __restrict__ src, const int* __restrict__ batch,
    float* __restrict__ epool, float* __restrict__ ce, int E)
{
    __shared__ float pool_s[32][64];
    __shared__ float cnt_s[32];
    int tid = threadIdx.x;
    for (int i = tid; i < 2048; i += 256) ((float*)pool_s)[i] = 0.f;
    if (tid < 32) cnt_s[tid] = 0.f;
    __syncthreads();
    int wv = tid >> 6, lane = tid & 63;
    int base = blockIdx.x * 256 + wv * 64;
    #pragma unroll 4
    for (int i = 0; i < 64; ++i) {
        int e = base + i;
        if (e < E) {
            int b = batch[src[e]];
            float val = ea[(size_t)e*64 + lane];
            atomicAdd(&pool_s[b][lane], val);
            if (lane == 0) atomicAdd(&cnt_s[b], 1.f);
        }
    }
    __syncthreads();
    for (int i = tid; i < 2048; i += 256) atomicAdd(epool + i, ((float*)pool_s)[i]);
    if (tid < 32) atomicAdd(ce + tid, cnt_s[tid]);
}

__global__ void __launch_bounds__(64) k_head_mlp(
    const float* __restrict__ npool, const float* __restrict__ epool,
    const float* __restrict__ cn, const float* __restrict__ ce,
    const float* __restrict__ rW1, const float* __restrict__ rb1,
    const float* __restrict__ rW2, const float* __restrict__ rb2,
    const float* __restrict__ rW3, const float* __restrict__ rb3,
    float* __restrict__ out)
{
    __shared__ float g[128];
    __shared__ float h1[64];
    __shared__ float h2[64];
    int b = blockIdx.x, lane = threadIdx.x;
    float cnv = fmaxf(cn[b], 1.f), cev = fmaxf(ce[b], 1.f);
    g[lane]      = npool[(size_t)b*64 + lane] / cnv;
    g[64 + lane] = epool[(size_t)b*64 + lane] / cev;
    __syncthreads();
    float acc = rb1[lane];
    #pragma unroll 4
    for (int j = 0; j < 128; ++j) acc += g[j] * rW1[j*64 + lane];
    h1[lane] = fmaxf(acc, 0.f);
    __syncthreads();
    acc = rb2[lane];
    #pragma unroll 4
    for (int j = 0; j < 64; ++j) acc += h1[j] * rW2[j*64 + lane];
    h2[lane] = fmaxf(acc, 0.f);
    __syncthreads();
    if (lane < 2) {
        float o = rb3[lane];
        for (int j = 0; j < 64; ++j) o += h2[j] * rW3[j*2 + lane];
        out[b*2 + lane] = tanhf(o);
    }
}

// ---------------- launcher ----------------

extern "C" void kernel_launch(void* const* d_in, const int* in_sizes, int n_in,
                              void* d_out, int out_size, void* d_ws, size_t ws_size,
                              hipStream_t stream)
{
    const float* x         = (const float*)d_in[0];
    const float* edge_attr = (const float*)d_in[1];
    const float* means     = (const float*)d_in[2];
    const float* log_stds  = (const float*)d_in[3];
    const float* spW       = (const float*)d_in[4];
    const float* spb       = (const float*)d_in[5];
    const float* neW       = (const float*)d_in[6];
    const float* neb       = (const float*)d_in[7];
    const float* eeW       = (const float*)d_in[8];
    const float* eeb       = (const float*)d_in[9];
    const float* Wq        = (const float*)d_in[10];
    const float* bq        = (const float*)d_in[11];
    const float* Wk        = (const float*)d_in[12];
    const float* bk        = (const float*)d_in[13];
    const float* Wv        = (const float*)d_in[14];
    const float* bv        = (const float*)d_in[15];
    const float* We        = (const float*)d_in[16];
    const float* be        = (const float*)d_in[17];
    const float* Ws        = (const float*)d_in[18];
    const float* bs        = (const float*)d_in[19];
    const float* euW       = (const float*)d_in[20];
    const float* eub       = (const float*)d_in[21];
    const float* rW1       = (const float*)d_in[22];
    const float* rb1       = (const float*)d_in[23];
    const float* rW2       = (const float*)d_in[24];
    const float* rb2       = (const float*)d_in[25];
    const float* rW3       = (const float*)d_in[26];
    const float* rb3       = (const float*)d_in[27];
    const int* eidx        = (const int*)d_in[28];
    const int* batch       = (const int*)d_in[29];

    int N = in_sizes[0] / 7;
    int E = in_sizes[1] / 4;
    const int G = 32;
    const int* srcp = eidx;
    const int* dstp = eidx + E;

    float* ws = (float*)d_ws;
    size_t fl = 0;
    float* hA    = ws + fl; fl += (size_t)N * 64;
    float* hB    = ws + fl; fl += (size_t)N * 64;
    float* eaA   = ws + fl; fl += (size_t)E * 64;
    float* eaB   = ws + fl; fl += (size_t)E * 64;
    float* B1    = ws + fl; fl += (size_t)N * 512;   // q, then v, then pbuf0..7 (st-major)
    float* B2    = ws + fl; fl += (size_t)N * 512;   // k, then vsum (N*64) | pbuf8 (N*64)
    float* B3    = ws + fl; fl += (size_t)N * 512;   // qe, then tbuf
    float* alpha = ws + fl; fl += (size_t)E * 8;     // also wbuf (E*4) at init
    float* mbuf  = ws + fl; fl += (size_t)N * 8;
    float* dbuf  = ws + fl; fl += (size_t)N * 8;
    float* sbuf  = ws + fl; fl += (size_t)N * 8;
    float* npool = ws + fl; fl += (size_t)G * 64;
    float* epool = ws + fl; fl += (size_t)G * 64;
    float* cn    = ws + fl; fl += G;
    float* ce    = ws + fl; fl += G;
    int* ideg  = (int*)(ws + fl); fl += (size_t)N;
    int* iptr  = (int*)(ws + fl); fl += (size_t)N + 1;
    int* ihead = (int*)(ws + fl); fl += (size_t)N;
    int* iperm = (int*)(ws + fl); fl += (size_t)E;
    // total ~47.5M floats = 190.1 MB (ws known >= 194 MB from round 1)

    float* wbuf = alpha;   // E*4 <= E*8, dead before alpha is first written

    hipMemsetAsync(npool, 0, (size_t)(G * 130) * sizeof(float), stream);
    hipMemsetAsync(ideg, 0, (size_t)N * sizeof(int), stream);

    k_node_embed<<<(N * 64 + 255) / 256, 256, 0, stream>>>(x, neW, neb, hA, N);
    k_edge_w<<<(E + 255) / 256, 256, 0, stream>>>(x, means, log_stds, srcp, dstp, wbuf, E);
    k_edge_ea<<<((size_t)E * 64 + 255) / 256, 256, 0, stream>>>(edge_attr, wbuf,
                                                                spW, spb, eeW, eeb, eaA, E);
    k_hist<<<(E + 255) / 256, 256, 0, stream>>>(dstp, ideg, E);
    k_scan<<<1, 1024, 0, stream>>>(ideg, iptr, ihead, N);
    k_scatter<<<(E + 255) / 256, 256, 0, stream>>>(dstp, ihead, iperm, E);

    float* hcur = hA;  float* hnext = hB;
    float* eacur = eaA; float* eanext = eaB;
    for (int l = 0; l < 3; ++l) {
        const float* Wq_l = Wq + (size_t)l * 64 * 512;
        const float* Wk_l = Wk + (size_t)l * 64 * 512;
        const float* Wv_l = Wv + (size_t)l * 64 * 512;
        const float* We_l = We + (size_t)l * 64 * 512;
        const float* be_l = be + (size_t)l * 512;

        k_gemm512_r32<<<(N + 31) / 32, 256, 0, stream>>>(hcur, Wq_l, bq + (size_t)l * 512, B1, N);
        k_gemm512_r32<<<(N + 31) / 32, 256, 0, stream>>>(hcur, Wk_l, bk + (size_t)l * 512, B2, N);
        k_qe<<<dim3((N + 31) / 32, 8), 256, 0, stream>>>(B1, We_l, B3, N);
        k_attn_alpha<<<(N + 3) / 4, 256, 0, stream>>>(B1, B2, B3, be_l, eacur,
                                                      iptr, iperm, srcp, alpha, mbuf, dbuf, N);
        k_gemm512_r32<<<(N + 31) / 32, 256, 0, stream>>>(hcur, Wv_l, bv + (size_t)l * 512, B1, N);
        k_attn_agg<<<(N + 3) / 4, 256, 0, stream>>>(alpha, mbuf, dbuf, B1, eacur,
                                                    iptr, iperm, srcp, B2, B3, sbuf, N);
        // node_finish as 9-way K-split partial GEMM + streaming reduce
        float* pbuf0 = B1;                       // v dead; 8 * N*64 = N*512 exactly
        float* pbuf8 = B2 + (size_t)N * 64;      // behind vsum
        k_nf_gemm<<<dim3((N + 63) / 64, 9), 256, 0, stream>>>(B3, hcur, We_l,
                                                              Ws + (size_t)l * 64 * 64,
                                                              pbuf0, pbuf8, N);
        k_nf_reduce<<<((size_t)N * 64 + 255) / 256, 256, 0, stream>>>(B2, pbuf0, pbuf8, sbuf,
                                                                      be_l, bs + (size_t)l * 64,
                                                                      hnext, N);
        k_edge_update<<<(E + 31) / 32, 256, 0, stream>>>(hnext, eacur, euW + (size_t)l * 192 * 64,
                                                         eub + (size_t)l * 64, srcp, dstp, eanext, E);
        float* t1 = hcur; hcur = hnext; hnext = t1;
        float* t2 = eacur; eacur = eanext; eanext = t2;
    }

    k_node_pool<<<(N + 63) / 64, 64, 0, stream>>>(hcur, batch, npool, cn, N);
    k_edge_pool<<<(E + 255) / 256, 256, 0, stream>>>(eacur, srcp, batch, epool, ce, E);
    k_head_mlp<<<G, 64, 0, stream>>>(npool, epool, cn, ce, rW1, rb1, rW2, rb2, rW3, rb3,
                                     (float*)d_out);
}

// Round 7
// 1215.184 us; speedup vs baseline: 1.1426x; 1.0037x over previous
//
#include <hip/hip_runtime.h>
#include <hip/hip_bf16.h>
#include <cstdint>
#include <cstddef>

// N=20000, E=100000, G=32, HID=64, HEADS=8, HC=64, HO=512, L=3, K=4. All fp32.
// e = ea@We+be only appears inside q·(k+e) and Σ a(v+e):
//   q·e|_h = ea · qe[dst]|_h,  qe[d][h*64+j] = Σ_c q[d][64h+c] We[j][64h+c]
//   Σ a e  = (Σ a ea) @ We + (Σ a) be   -> all We GEMMs at N-level.
// R6: node_finish K-split into 9 grid-y partials (occupancy fix, 121us -> off top-5).
// R7: k_edge_update was LDS-issue-bound (1536 scalar ds_read_b32 vs 1536 FMA/thread)
//     -> float4 LDS reads (b128, 4x fewer LDS instrs). attn chains shortened via
//     srcg[it]=src[perm[it]] precompute + CSR-slot-indexed alpha.

// ---------------- embed / init ----------------

__global__ void __launch_bounds__(256) k_node_embed(
    const float* __restrict__ x, const float* __restrict__ neW, const float* __restrict__ neb,
    float* __restrict__ h, int N)
{
    int idx = blockIdx.x * 256 + threadIdx.x;
    int n = idx >> 6, c = idx & 63;
    if (n >= N) return;
    float acc = neb[c];
    #pragma unroll
    for (int j = 0; j < 7; ++j) acc += x[(size_t)n * 7 + j] * neW[j * 64 + c];
    h[(size_t)n * 64 + c] = fmaxf(acc, 0.f);
}

__global__ void __launch_bounds__(256) k_edge_w(
    const float* __restrict__ x,
    const float* __restrict__ means, const float* __restrict__ log_stds,
    const int* __restrict__ src, const int* __restrict__ dst,
    float* __restrict__ wbuf, int E)
{
    int e = blockIdx.x * 256 + threadIdx.x;
    if (e >= E) return;
    int s = src[e], d = dst[e];
    const float* ps = x + (size_t)s * 7;
    const float* pd = x + (size_t)d * 7;
    float slx = ps[0], sly = ps[1], srx = ps[2], sry = ps[3];
    float dlx = pd[0], dly = pd[1], drx = pd[2], dry = pd[3];
    float u[8];
    float rx, ry;
    rx = dlx - slx; ry = dly - sly; u[0] = sqrtf(rx*rx + ry*ry); u[1] = atan2f(ry, rx);
    rx = dlx - srx; ry = dly - sry; u[2] = sqrtf(rx*rx + ry*ry); u[3] = atan2f(ry, rx);
    rx = drx - slx; ry = dry - sly; u[4] = sqrtf(rx*rx + ry*ry); u[5] = atan2f(ry, rx);
    rx = drx - srx; ry = dry - sry; u[6] = sqrtf(rx*rx + ry*ry); u[7] = atan2f(ry, rx);
    #pragma unroll
    for (int kk = 0; kk < 4; ++kk) {
        float ssum = 0.f;
        #pragma unroll
        for (int dd = 0; dd < 8; ++dd) {
            float stdv = expf(log_stds[kk*8+dd]) + 1e-6f;
            float z = (u[dd] - means[kk*8+dd]) / stdv;
            ssum += z * z;
        }
        wbuf[(size_t)e*4 + kk] = expf(-0.5f * ssum);
    }
}

__global__ void __launch_bounds__(256) k_edge_ea(
    const float* __restrict__ edge_attr, const float* __restrict__ wbuf,
    const float* __restrict__ spW, const float* __restrict__ spb,
    const float* __restrict__ eeW, const float* __restrict__ eeb,
    float* __restrict__ ea, int E)
{
    int idx = blockIdx.x * 256 + threadIdx.x;
    int e = idx >> 6, c = idx & 63;
    if (e >= E) return;
    float acce = eeb[c];
    #pragma unroll
    for (int j = 0; j < 4; ++j) acce += edge_attr[(size_t)e*4 + j] * eeW[j*64 + c];
    float accs = spb[c];
    #pragma unroll
    for (int j = 0; j < 4; ++j) accs += wbuf[(size_t)e*4 + j] * spW[j*64 + c];
    ea[(size_t)e*64 + c] = fmaxf(acce, 0.f) + fmaxf(accs, 0.f);
}

// ---------------- CSR build ----------------

__global__ void __launch_bounds__(256) k_hist(
    const int* __restrict__ dst, int* __restrict__ deg, int E)
{
    int e = blockIdx.x * 256 + threadIdx.x;
    if (e < E) atomicAdd(deg + dst[e], 1);
}

__global__ void __launch_bounds__(1024) k_scan(
    const int* __restrict__ deg, int* __restrict__ ptr, int* __restrict__ headw, int N)
{
    __shared__ int part[1024];
    int t = threadIdx.x;
    int per = (N + 1023) / 1024;
    int s = 0;
    for (int i = 0; i < per; ++i) { int idx = t*per + i; if (idx < N) s += deg[idx]; }
    part[t] = s;
    __syncthreads();
    for (int off = 1; off < 1024; off <<= 1) {
        int v = (t >= off) ? part[t - off] : 0;
        __syncthreads();
        part[t] += v;
        __syncthreads();
    }
    int base = (t > 0) ? part[t - 1] : 0;
    for (int i = 0; i < per; ++i) {
        int idx = t*per + i;
        if (idx < N) { ptr[idx] = base; headw[idx] = base; base += deg[idx]; }
    }
    if (t == 1023) ptr[N] = part[1023];
}

// perm[pos] = e, srcg[pos] = src[e]  (kills the perm->src dependent-load chain)
__global__ void __launch_bounds__(256) k_scatter(
    const int* __restrict__ dst, const int* __restrict__ src,
    int* __restrict__ headw, int* __restrict__ perm, int* __restrict__ srcg, int E)
{
    int e = blockIdx.x * 256 + threadIdx.x;
    if (e < E) {
        int pos = atomicAdd(headw + dst[e], 1);
        perm[pos] = e;
        srcg[pos] = src[e];
    }
}

// ---------------- GEMMs ----------------

__global__ void __launch_bounds__(256) k_gemm512_r32(
    const float* __restrict__ X, const float* __restrict__ W, const float* __restrict__ bias,
    float* __restrict__ Y, int M)
{
    __shared__ __align__(16) float xs[32][64];
    int tid = threadIdx.x;
    int r0 = blockIdx.x * 32;
    for (int i = tid; i < 2048; i += 256) {
        int r = i >> 6, c = i & 63;
        int rr = r0 + r;
        xs[r][c] = (rr < M) ? X[(size_t)rr * 64 + c] : 0.f;
    }
    __syncthreads();
    int wv = tid >> 6, lane = tid & 63;
    int c0 = lane * 8;
    float acc[8][8];
    float4 b0 = *(const float4*)(bias + c0);
    float4 b1 = *(const float4*)(bias + c0 + 4);
    #pragma unroll
    for (int t = 0; t < 8; ++t) {
        acc[t][0]=b0.x; acc[t][1]=b0.y; acc[t][2]=b0.z; acc[t][3]=b0.w;
        acc[t][4]=b1.x; acc[t][5]=b1.y; acc[t][6]=b1.z; acc[t][7]=b1.w;
    }
    #pragma unroll 2
    for (int j = 0; j < 64; ++j) {
        float4 wa = *(const float4*)(W + (size_t)j*512 + c0);
        float4 wb = *(const float4*)(W + (size_t)j*512 + c0 + 4);
        #pragma unroll
        for (int t = 0; t < 8; ++t) {
            float a = xs[wv*8 + t][j];
            acc[t][0] += a*wa.x; acc[t][1] += a*wa.y; acc[t][2] += a*wa.z; acc[t][3] += a*wa.w;
            acc[t][4] += a*wb.x; acc[t][5] += a*wb.y; acc[t][6] += a*wb.z; acc[t][7] += a*wb.w;
        }
    }
    #pragma unroll
    for (int t = 0; t < 8; ++t) {
        int r = r0 + wv*8 + t;
        if (r < M) {
            float4 o0 = {acc[t][0],acc[t][1],acc[t][2],acc[t][3]};
            float4 o1 = {acc[t][4],acc[t][5],acc[t][6],acc[t][7]};
            *(float4*)(Y + (size_t)r*512 + c0)     = o0;
            *(float4*)(Y + (size_t)r*512 + c0 + 4) = o1;
        }
    }
}

// qe[d][h*64+j] = sum_c q[d][64h+c] * We[j][64h+c].  grid: ((N+31)/32, 8)
__global__ void __launch_bounds__(256) k_qe(
    const float* __restrict__ q, const float* __restrict__ We,
    float* __restrict__ qe, int N)
{
    __shared__ __align__(16) float qlds[32][64];
    __shared__ float welds[64][65];
    int tid = threadIdx.x;
    int h = blockIdx.y;
    int n0 = blockIdx.x * 32;
    for (int i = tid; i < 2048; i += 256) {
        int r = i >> 6, c = i & 63;
        int n = n0 + r;
        qlds[r][c] = (n < N) ? q[(size_t)n*512 + h*64 + c] : 0.f;
    }
    for (int i = tid; i < 4096; i += 256) {
        int j = i >> 6, c = i & 63;
        welds[j][c] = We[(size_t)j*512 + h*64 + c];
    }
    __syncthreads();
    int wv = tid >> 6, lane = tid & 63;   // lane = j
    float acc[8];
    #pragma unroll
    for (int r = 0; r < 8; ++r) acc[r] = 0.f;
    #pragma unroll 4
    for (int c = 0; c < 64; ++c) {
        float w = welds[lane][c];
        #pragma unroll
        for (int r = 0; r < 8; ++r) acc[r] += qlds[wv*8 + r][c] * w;
    }
    #pragma unroll
    for (int r = 0; r < 8; ++r) {
        int n = n0 + wv*8 + r;
        if (n < N) qe[(size_t)n*512 + h*64 + lane] = acc[r];
    }
}

// ---------------- CSR-fused attention ----------------

__global__ void __launch_bounds__(256) k_attn_alpha(
    const float* __restrict__ q, const float* __restrict__ k, const float* __restrict__ qe,
    const float* __restrict__ be, const float* __restrict__ ea,
    const int* __restrict__ ptr, const int* __restrict__ perm, const int* __restrict__ srcg,
    float* __restrict__ alpha, float* __restrict__ mbuf, float* __restrict__ dbuf, int N)
{
    int wv = threadIdx.x >> 6, lane = threadIdx.x & 63;
    int n = blockIdx.x * 4 + wv;
    if (n >= N) return;
    int h = lane >> 3, p = lane & 7;
    int b = ptr[n], e_ = ptr[n + 1];
    const float4* qp = (const float4*)(q + (size_t)n*512 + lane*8);
    float4 q0 = qp[0], q1 = qp[1];
    const float4* qep = (const float4*)(qe + (size_t)n*512 + lane*8);
    float4 g0 = qep[0], g1 = qep[1];
    const float4* bep = (const float4*)(be + lane*8);
    float4 b0 = bep[0], b1 = bep[1];
    float qbe = q0.x*b0.x + q0.y*b0.y + q0.z*b0.z + q0.w*b0.w
              + q1.x*b1.x + q1.y*b1.y + q1.z*b1.z + q1.w*b1.w;
    qbe += __shfl_xor(qbe, 1);
    qbe += __shfl_xor(qbe, 2);
    qbe += __shfl_xor(qbe, 4);
    float m = -3.4e38f, den = 0.f;
    for (int it = b; it < e_; ++it) {
        int s = srcg[it];
        int e = perm[it];
        const float4* kp = (const float4*)(k + (size_t)s*512 + lane*8);
        float4 k0 = kp[0], k1 = kp[1];
        const float4* ap = (const float4*)(ea + (size_t)e*64 + p*8);
        float4 a0 = ap[0], a1 = ap[1];
        float t = q0.x*k0.x + q0.y*k0.y + q0.z*k0.z + q0.w*k0.w
                + q1.x*k1.x + q1.y*k1.y + q1.z*k1.z + q1.w*k1.w
                + a0.x*g0.x + a0.y*g0.y + a0.z*g0.z + a0.w*g0.w
                + a1.x*g1.x + a1.y*g1.y + a1.z*g1.z + a1.w*g1.w;
        t += __shfl_xor(t, 1);
        t += __shfl_xor(t, 2);
        t += __shfl_xor(t, 4);
        float al = 0.125f * (t + qbe);
        float mn = fmaxf(m, al);
        den = den * expf(m - mn) + expf(al - mn);
        m = mn;
        if (p == 0) alpha[(size_t)it*8 + h] = al;   // CSR-slot indexed
    }
    if (p == 0) {
        mbuf[(size_t)n*8 + h] = m;
        dbuf[(size_t)n*8 + h] = den;
    }
}

// vsum[n][cc] = Σ_h Σ_e a v[s][64h+cc] (head-reduced in-register via shfl);
// tbuf[n][h*64+j] = Σ a_h ea[j]; sbuf[n][h] = Σ a_h.
__global__ void __launch_bounds__(256) k_attn_agg(
    const float* __restrict__ alpha, const float* __restrict__ mbuf, const float* __restrict__ dbuf,
    const float* __restrict__ v, const float* __restrict__ ea,
    const int* __restrict__ ptr, const int* __restrict__ perm, const int* __restrict__ srcg,
    float* __restrict__ vsum, float* __restrict__ tbuf, float* __restrict__ sbuf, int N)
{
    int wv = threadIdx.x >> 6, lane = threadIdx.x & 63;
    int n = blockIdx.x * 4 + wv;
    if (n >= N) return;
    int h = lane >> 3, p = lane & 7;
    int b = ptr[n], e_ = ptr[n + 1];
    float m = mbuf[(size_t)n*8 + h];
    float inv = 0.125f / (dbuf[(size_t)n*8 + h] + 1e-16f);   // 1/HEADS folded in
    float vacc[8], tacc[8];
    #pragma unroll
    for (int i = 0; i < 8; ++i) { vacc[i] = 0.f; tacc[i] = 0.f; }
    float sacc = 0.f;
    for (int it = b; it < e_; ++it) {
        int s = srcg[it];
        int e = perm[it];
        float a = expf(alpha[(size_t)it*8 + h] - m) * inv;
        sacc += a;
        const float4* vp = (const float4*)(v + (size_t)s*512 + lane*8);
        float4 v0 = vp[0], v1 = vp[1];
        const float4* ap = (const float4*)(ea + (size_t)e*64 + p*8);
        float4 a0 = ap[0], a1 = ap[1];
        vacc[0] += a*v0.x; vacc[1] += a*v0.y; vacc[2] += a*v0.z; vacc[3] += a*v0.w;
        vacc[4] += a*v1.x; vacc[5] += a*v1.y; vacc[6] += a*v1.z; vacc[7] += a*v1.w;
        tacc[0] += a*a0.x; tacc[1] += a*a0.y; tacc[2] += a*a0.z; tacc[3] += a*a0.w;
        tacc[4] += a*a1.x; tacc[5] += a*a1.y; tacc[6] += a*a1.z; tacc[7] += a*a1.w;
    }
    #pragma unroll
    for (int i = 0; i < 8; ++i) {
        vacc[i] += __shfl_xor(vacc[i], 8);
        vacc[i] += __shfl_xor(vacc[i], 16);
        vacc[i] += __shfl_xor(vacc[i], 32);
    }
    float4 o;
    if (lane < 8) {
        o = {vacc[0],vacc[1],vacc[2],vacc[3]}; *(float4*)(vsum + (size_t)n*64 + lane*8)     = o;
        o = {vacc[4],vacc[5],vacc[6],vacc[7]}; *(float4*)(vsum + (size_t)n*64 + lane*8 + 4) = o;
    }
    o = {tacc[0],tacc[1],tacc[2],tacc[3]}; *(float4*)(tbuf + (size_t)n*512 + lane*8)     = o;
    o = {tacc[4],tacc[5],tacc[6],tacc[7]}; *(float4*)(tbuf + (size_t)n*512 + lane*8 + 4) = o;
    if (p == 0) sbuf[(size_t)n*8 + h] = sacc;
}

// Partial GEMM, grid (ceil(N/64), 9):
//  st<8: pbuf0[st][n][cc] = Σ_j tbuf[n][st*64+j] * We[j][st*64+cc]
//  st=8: pbuf8[n][cc]     = Σ_j hin[n][j]       * Ws[j][cc]
__global__ void __launch_bounds__(256) k_nf_gemm(
    const float* __restrict__ tbuf, const float* __restrict__ hin,
    const float* __restrict__ We, const float* __restrict__ Ws,
    float* __restrict__ pbuf0, float* __restrict__ pbuf8, int N)
{
    __shared__ __align__(16) float At[64][64];
    __shared__ __align__(16) float Bt[64][64];
    int tid = threadIdx.x;
    int st = blockIdx.y;
    int n0 = blockIdx.x * 64;
    if (st < 8) {
        for (int i = tid; i < 4096; i += 256) {
            int r = i >> 6, c = i & 63;
            int n = n0 + r;
            At[r][c] = (n < N) ? tbuf[(size_t)n*512 + st*64 + c] : 0.f;
            Bt[r][c] = We[(size_t)r*512 + st*64 + c];
        }
    } else {
        for (int i = tid; i < 4096; i += 256) {
            int r = i >> 6, c = i & 63;
            int n = n0 + r;
            At[r][c] = (n < N) ? hin[(size_t)n*64 + c] : 0.f;
            Bt[r][c] = Ws[(size_t)r*64 + c];
        }
    }
    __syncthreads();
    int wv = tid >> 6, lane = tid & 63;
    float acc[16];
    #pragma unroll
    for (int r = 0; r < 16; ++r) acc[r] = 0.f;
    #pragma unroll 4
    for (int j = 0; j < 64; ++j) {
        float w = Bt[j][lane];
        #pragma unroll
        for (int r = 0; r < 16; ++r) acc[r] += At[wv*16 + r][j] * w;
    }
    float* out = (st < 8) ? (pbuf0 + (size_t)st * N * 64) : pbuf8;
    #pragma unroll
    for (int r = 0; r < 16; ++r) {
        int n = n0 + wv*16 + r;
        if (n < N) out[(size_t)n*64 + lane] = acc[r];
    }
}

// hnext = relu( vsum + Σ_st pbuf + pbuf8 + Σ_h sbuf·be + bs )
__global__ void __launch_bounds__(256) k_nf_reduce(
    const float* __restrict__ vsum, const float* __restrict__ pbuf0,
    const float* __restrict__ pbuf8, const float* __restrict__ sbuf,
    const float* __restrict__ be, const float* __restrict__ bs,
    float* __restrict__ hnext, int N)
{
    int idx = blockIdx.x * 256 + threadIdx.x;
    int n = idx >> 6, cc = idx & 63;
    if (n >= N) return;
    float a = bs[cc] + vsum[(size_t)n*64 + cc] + pbuf8[(size_t)n*64 + cc];
    #pragma unroll
    for (int st = 0; st < 8; ++st) a += pbuf0[(size_t)st*N*64 + (size_t)n*64 + cc];
    #pragma unroll
    for (int h = 0; h < 8; ++h) a += sbuf[(size_t)n*8 + h] * be[h*64 + cc];
    hnext[(size_t)n*64 + cc] = fmaxf(a, 0.f);
}

// ea2 = relu([h[src], h[dst], ea] @ euW + eub)  (192x64).
// float4 LDS broadcast reads: 4x fewer LDS instructions (was ds_read_b32-bound).
__global__ void __launch_bounds__(256) k_edge_update(
    const float* __restrict__ h, const float* __restrict__ ea,
    const float* __restrict__ euW, const float* __restrict__ eub,
    const int* __restrict__ src, const int* __restrict__ dst,
    float* __restrict__ ea2, int E)
{
    __shared__ __align__(16) float s_src[32][64];
    __shared__ __align__(16) float s_dst[32][64];
    __shared__ __align__(16) float s_ea[32][64];
    __shared__ int sid[32], did[32];
    int tid = threadIdx.x;
    int e0 = blockIdx.x * 32;
    if (tid < 32) {
        int e = e0 + tid; if (e >= E) e = E - 1;
        sid[tid] = src[e]; did[tid] = dst[e];
    }
    __syncthreads();
    for (int i = tid; i < 512; i += 256) {
        int r = i >> 4, c4 = (i & 15) * 4;
        int e = e0 + r; if (e >= E) e = E - 1;
        *(float4*)&s_src[r][c4] = *(const float4*)(h + (size_t)sid[r]*64 + c4);
        *(float4*)&s_dst[r][c4] = *(const float4*)(h + (size_t)did[r]*64 + c4);
        *(float4*)&s_ea[r][c4]  = *(const float4*)(ea + (size_t)e*64 + c4);
    }
    __syncthreads();
    int wv = tid >> 6, lane = tid & 63;
    float acc[8];
    float bv = eub[lane];
    #pragma unroll
    for (int t = 0; t < 8; ++t) acc[t] = bv;
    #pragma unroll 2
    for (int j4 = 0; j4 < 16; ++j4) {
        int j = j4 * 4;
        float w0 = euW[(size_t)(j+0)*64 + lane];
        float w1 = euW[(size_t)(j+1)*64 + lane];
        float w2 = euW[(size_t)(j+2)*64 + lane];
        float w3 = euW[(size_t)(j+3)*64 + lane];
        #pragma unroll
        for (int t = 0; t < 8; ++t) {
            float4 a = *(const float4*)&s_src[wv*8 + t][j];
            acc[t] += a.x*w0 + a.y*w1 + a.z*w2 + a.w*w3;
        }
    }
    #pragma unroll 2
    for (int j4 = 0; j4 < 16; ++j4) {
        int j = j4 * 4;
        float w0 = euW[(size_t)(64+j+0)*64 + lane];
        float w1 = euW[(size_t)(64+j+1)*64 + lane];
        float w2 = euW[(size_t)(64+j+2)*64 + lane];
        float w3 = euW[(size_t)(64+j+3)*64 + lane];
        #pragma unroll
        for (int t = 0; t < 8; ++t) {
            float4 a = *(const float4*)&s_dst[wv*8 + t][j];
            acc[t] += a.x*w0 + a.y*w1 + a.z*w2 + a.w*w3;
        }
    }
    #pragma unroll 2
    for (int j4 = 0; j4 < 16; ++j4) {
        int j = j4 * 4;
        float w0 = euW[(size_t)(128+j+0)*64 + lane];
        float w1 = euW[(size_t)(128+j+1)*64 + lane];
        float w2 = euW[(size_t)(128+j+2)*64 + lane];
        float w3 = euW[(size_t)(128+j+3)*64 + lane];
        #pragma unroll
        for (int t = 0; t < 8; ++t) {
            float4 a = *(const float4*)&s_ea[wv*8 + t][j];
            acc[t] += a.x*w0 + a.y*w1 + a.z*w2 + a.w*w3;
        }
    }
    #pragma unroll
    for (int t = 0; t < 8; ++t) {
        int e = e0 + wv*8 + t;
        if (e < E) ea2[(size_t)e*64 + lane] = fmaxf(acc[t], 0.f);
    }
}

// ---------------- pooling / head ----------------

__global__ void __launch_bounds__(64) k_node_pool(
    const float* __restrict__ h, const int* __restrict__ batch,
    float* __restrict__ npool, float* __restrict__ cn, int N)
{
    int lane = threadIdx.x;
    int n0 = blockIdx.x * 64;
    float acc = 0.f; int cur = -1; int run = 0;
    for (int i = 0; i < 64; ++i) {
        int n = n0 + i;
        if (n >= N) break;
        int b = batch[n];
        if (b != cur) {
            if (cur >= 0) {
                atomicAdd(npool + (size_t)cur*64 + lane, acc);
                if (lane == 0) atomicAdd(cn + cur, (float)run);
            }
            cur = b; acc = 0.f; run = 0;
        }
        acc += h[(size_t)n*64 + lane];
        ++run;
    }
    if (cur >= 0) {
        atomicAdd(npool + (size_t)cur*64 + lane, acc);
        if (lane == 0) atomicAdd(cn + cur, (float)run);
    }
}

__global__ void __launch_bounds__(256) k_edge_pool(
    const float* __restrict__ ea, const int* __restrict__ src, const int* __restrict__ batch,
    float* __restrict__ epool, float* __restrict__ ce, int E)
{
    __shared__ float pool_s[32][64];
    __shared__ float cnt_s[32];
    int tid = threadIdx.x;
    for (int i = tid; i < 2048; i += 256) ((float*)pool_s)[i] = 0.f;
    if (tid < 32) cnt_s[tid] = 0.f;
    __syncthreads();
    int wv = tid >> 6, lane = tid & 63;
    int base = blockIdx.x * 256 + wv * 64;
    #pragma unroll 4
    for (int i = 0; i < 64; ++i) {
        int e = base + i;
        if (e < E) {
            int b = batch[src[e]];
            float val = ea[(size_t)e*64 + lane];
            atomicAdd(&pool_s[b][lane], val);
            if (lane == 0) atomicAdd(&cnt_s[b], 1.f);
        }
    }
    __syncthreads();
    for (int i = tid; i < 2048; i += 256) atomicAdd(epool + i, ((float*)pool_s)[i]);
    if (tid < 32) atomicAdd(ce + tid, cnt_s[tid]);
}

__global__ void __launch_bounds__(64) k_head_mlp(
    const float* __restrict__ npool, const float* __restrict__ epool,
    const float* __restrict__ cn, const float* __restrict__ ce,
    const float* __restrict__ rW1, const float* __restrict__ rb1,
    const float* __restrict__ rW2, const float* __restrict__ rb2,
    const float* __restrict__ rW3, const float* __restrict__ rb3,
    float* __restrict__ out)
{
    __shared__ float g[128];
    __shared__ float h1[64];
    __shared__ float h2[64];
    int b = blockIdx.x, lane = threadIdx.x;
    float cnv = fmaxf(cn[b], 1.f), cev = fmaxf(ce[b], 1.f);
    g[lane]      = npool[(size_t)b*64 + lane] / cnv;
    g[64 + lane] = epool[(size_t)b*64 + lane] / cev;
    __syncthreads();
    float acc = rb1[lane];
    #pragma unroll 4
    for (int j = 0; j < 128; ++j) acc += g[j] * rW1[j*64 + lane];
    h1[lane] = fmaxf(acc, 0.f);
    __syncthreads();
    acc = rb2[lane];
    #pragma unroll 4
    for (int j = 0; j < 64; ++j) acc += h1[j] * rW2[j*64 + lane];
    h2[lane] = fmaxf(acc, 0.f);
    __syncthreads();
    if (lane < 2) {
        float o = rb3[lane];
        for (int j = 0; j < 64; ++j) o += h2[j] * rW3[j*2 + lane];
        out[b*2 + lane] = tanhf(o);
    }
}

// ---------------- launcher ----------------

extern "C" void kernel_launch(void* const* d_in, const int* in_sizes, int n_in,
                              void* d_out, int out_size, void* d_ws, size_t ws_size,
                              hipStream_t stream)
{
    const float* x         = (const float*)d_in[0];
    const float* edge_attr = (const float*)d_in[1];
    const float* means     = (const float*)d_in[2];
    const float* log_stds  = (const float*)d_in[3];
    const float* spW       = (const float*)d_in[4];
    const float* spb       = (const float*)d_in[5];
    const float* neW       = (const float*)d_in[6];
    const float* neb       = (const float*)d_in[7];
    const float* eeW       = (const float*)d_in[8];
    const float* eeb       = (const float*)d_in[9];
    const float* Wq        = (const float*)d_in[10];
    const float* bq        = (const float*)d_in[11];
    const float* Wk        = (const float*)d_in[12];
    const float* bk        = (const float*)d_in[13];
    const float* Wv        = (const float*)d_in[14];
    const float* bv        = (const float*)d_in[15];
    const float* We        = (const float*)d_in[16];
    const float* be        = (const float*)d_in[17];
    const float* Ws        = (const float*)d_in[18];
    const float* bs        = (const float*)d_in[19];
    const float* euW       = (const float*)d_in[20];
    const float* eub       = (const float*)d_in[21];
    const float* rW1       = (const float*)d_in[22];
    const float* rb1       = (const float*)d_in[23];
    const float* rW2       = (const float*)d_in[24];
    const float* rb2       = (const float*)d_in[25];
    const float* rW3       = (const float*)d_in[26];
    const float* rb3       = (const float*)d_in[27];
    const int* eidx        = (const int*)d_in[28];
    const int* batch       = (const int*)d_in[29];

    int N = in_sizes[0] / 7;
    int E = in_sizes[1] / 4;
    const int G = 32;
    const int* srcp = eidx;
    const int* dstp = eidx + E;

    float* ws = (float*)d_ws;
    size_t fl = 0;
    float* hA    = ws + fl; fl += (size_t)N * 64;
    float* hB    = ws + fl; fl += (size_t)N * 64;
    float* eaA   = ws + fl; fl += (size_t)E * 64;
    float* eaB   = ws + fl; fl += (size_t)E * 64;
    float* B1    = ws + fl; fl += (size_t)N * 512;   // q, then v, then pbuf0..7 (st-major)
    float* B2    = ws + fl; fl += (size_t)N * 512;   // k, then vsum (N*64) | pbuf8 (N*64)
    float* B3    = ws + fl; fl += (size_t)N * 512;   // qe, then tbuf
    float* alpha = ws + fl; fl += (size_t)E * 8;     // also wbuf (E*4) at init
    float* mbuf  = ws + fl; fl += (size_t)N * 8;
    float* dbuf  = ws + fl; fl += (size_t)N * 8;
    float* sbuf  = ws + fl; fl += (size_t)N * 8;
    float* npool = ws + fl; fl += (size_t)G * 64;
    float* epool = ws + fl; fl += (size_t)G * 64;
    float* cn    = ws + fl; fl += G;
    float* ce    = ws + fl; fl += G;
    int* ideg  = (int*)(ws + fl); fl += (size_t)N;
    int* iptr  = (int*)(ws + fl); fl += (size_t)N + 1;
    int* ihead = (int*)(ws + fl); fl += (size_t)N;
    int* iperm = (int*)(ws + fl); fl += (size_t)E;
    int* isrcg = (int*)(ws + fl); fl += (size_t)E;
    // total ~47.6M floats = 190.5 MB (ws known >= 194 MB from round 1)

    float* wbuf = alpha;   // E*4 <= E*8, dead before alpha is first written

    hipMemsetAsync(npool, 0, (size_t)(G * 130) * sizeof(float), stream);
    hipMemsetAsync(ideg, 0, (size_t)N * sizeof(int), stream);

    k_node_embed<<<(N * 64 + 255) / 256, 256, 0, stream>>>(x, neW, neb, hA, N);
    k_edge_w<<<(E + 255) / 256, 256, 0, stream>>>(x, means, log_stds, srcp, dstp, wbuf, E);
    k_edge_ea<<<((size_t)E * 64 + 255) / 256, 256, 0, stream>>>(edge_attr, wbuf,
                                                                spW, spb, eeW, eeb, eaA, E);
    k_hist<<<(E + 255) / 256, 256, 0, stream>>>(dstp, ideg, E);
    k_scan<<<1, 1024, 0, stream>>>(ideg, iptr, ihead, N);
    k_scatter<<<(E + 255) / 256, 256, 0, stream>>>(dstp, srcp, ihead, iperm, isrcg, E);

    float* hcur = hA;  float* hnext = hB;
    float* eacur = eaA; float* eanext = eaB;
    for (int l = 0; l < 3; ++l) {
        const float* Wq_l = Wq + (size_t)l * 64 * 512;
        const float* Wk_l = Wk + (size_t)l * 64 * 512;
        const float* Wv_l = Wv + (size_t)l * 64 * 512;
        const float* We_l = We + (size_t)l * 64 * 512;
        const float* be_l = be + (size_t)l * 512;

        k_gemm512_r32<<<(N + 31) / 32, 256, 0, stream>>>(hcur, Wq_l, bq + (size_t)l * 512, B1, N);
        k_gemm512_r32<<<(N + 31) / 32, 256, 0, stream>>>(hcur, Wk_l, bk + (size_t)l * 512, B2, N);
        k_qe<<<dim3((N + 31) / 32, 8), 256, 0, stream>>>(B1, We_l, B3, N);
        k_attn_alpha<<<(N + 3) / 4, 256, 0, stream>>>(B1, B2, B3, be_l, eacur,
                                                      iptr, iperm, isrcg, alpha, mbuf, dbuf, N);
        k_gemm512_r32<<<(N + 31) / 32, 256, 0, stream>>>(hcur, Wv_l, bv + (size_t)l * 512, B1, N);
        k_attn_agg<<<(N + 3) / 4, 256, 0, stream>>>(alpha, mbuf, dbuf, B1, eacur,
                                                    iptr, iperm, isrcg, B2, B3, sbuf, N);
        float* pbuf0 = B1;                       // v dead; 8 * N*64 = N*512 exactly
        float* pbuf8 = B2 + (size_t)N * 64;      // behind vsum
        k_nf_gemm<<<dim3((N + 63) / 64, 9), 256, 0, stream>>>(B3, hcur, We_l,
                                                              Ws + (size_t)l * 64 * 64,
                                                              pbuf0, pbuf8, N);
        k_nf_reduce<<<((size_t)N * 64 + 255) / 256, 256, 0, stream>>>(B2, pbuf0, pbuf8, sbuf,
                                                                      be_l, bs + (size_t)l * 64,
                                                                      hnext, N);
        k_edge_update<<<(E + 31) / 32, 256, 0, stream>>>(hnext, eacur, euW + (size_t)l * 192 * 64,
                                                         eub + (size_t)l * 64, srcp, dstp, eanext, E);
        float* t1 = hcur; hcur = hnext; hnext = t1;
        float* t2 = eacur; eacur = eanext; eanext = t2;
    }

    k_node_pool<<<(N + 63) / 64, 64, 0, stream>>>(hcur, batch, npool, cn, N);
    k_edge_pool<<<(E + 255) / 256, 256, 0, stream>>>(eacur, srcp, batch, epool, ce, E);
    k_head_mlp<<<G, 64, 0, stream>>>(npool, epool, cn, ce, rW1, rb1, rW2, rb2, rW3, rb3,
                                     (float*)d_out);
}